// Round 1
// baseline (560.389 us; speedup 1.0000x reference)
//
#include <hip/hip_runtime.h>
#include <hip/hip_bf16.h>

// GIN layer: out = relu(((1+eps)*x + segment_sum(x[src], dst)) @ W1 + b1) @ W2 + b2
// N=50000 nodes, E=1.6M edges, D=128.

#define N_NODES 50000
#define N_EDGES 1600000
#define D 128

// ---------------- edge dtype detection ----------------
// If edge_index is int64 (little-endian, values < 50000), every odd int32 word
// of the buffer is 0. If int32, odd words are random node ids (P(all 256 == 0) ~ 0).
__global__ void k_detect(const int* __restrict__ ei, int* __restrict__ flag) {
    __shared__ int nz;
    if (threadIdx.x == 0) nz = 0;
    __syncthreads();
    int v = ei[threadIdx.x * 2 + 1];
    if (v != 0) atomicAdd(&nz, 1);
    __syncthreads();
    if (threadIdx.x == 0) *flag = (nz == 0) ? 1 : 0;  // 1 => int64 layout
}

__device__ inline int edge_get(const int* __restrict__ ei, long long logical_idx, int wide) {
    return wide ? ei[logical_idx * 2] : ei[(int)logical_idx == logical_idx ? (int)logical_idx : 0,
                                           logical_idx];
}

// ---------------- degree histogram ----------------
__global__ void k_zero(int* __restrict__ deg) {
    int i = blockIdx.x * blockDim.x + threadIdx.x;
    if (i < N_NODES) deg[i] = 0;
}

__global__ void k_hist(const int* __restrict__ ei, const int* __restrict__ flag,
                       int* __restrict__ deg) {
    int e = blockIdx.x * blockDim.x + threadIdx.x;
    if (e >= N_EDGES) return;
    int wide = *flag;
    long long di = (long long)N_EDGES + e;
    int d = wide ? ei[di * 2] : ei[di];
    if ((unsigned)d < (unsigned)N_NODES) atomicAdd(&deg[d], 1);
}

// ---------------- exclusive prefix scan over 50000 (single block) ----------------
__global__ __launch_bounds__(1024) void k_scan(const int* __restrict__ deg,
                                               int* __restrict__ offsets,
                                               int* __restrict__ cursor) {
    __shared__ int sums[1024];
    int t = threadIdx.x;
    const int CH = (N_NODES + 1023) / 1024;  // 49
    int b = t * CH;
    int e = b + CH; if (e > N_NODES) e = N_NODES;
    int s = 0;
    for (int i = b; i < e; ++i) s += deg[i];
    sums[t] = s;
    __syncthreads();
    for (int off = 1; off < 1024; off <<= 1) {
        int v = (t >= off) ? sums[t - off] : 0;
        __syncthreads();
        sums[t] += v;
        __syncthreads();
    }
    int run = (t == 0) ? 0 : sums[t - 1];
    for (int i = b; i < e; ++i) {
        int dg = deg[i];
        offsets[i] = run;
        cursor[i] = run;
        run += dg;
    }
}

// ---------------- CSR fill ----------------
__global__ void k_fill(const int* __restrict__ ei, const int* __restrict__ flag,
                       int* __restrict__ cursor, int* __restrict__ srcs) {
    int e = blockIdx.x * blockDim.x + threadIdx.x;
    if (e >= N_EDGES) return;
    int wide = *flag;
    int s = wide ? ei[(long long)e * 2] : ei[e];
    long long di = (long long)N_EDGES + e;
    int d = wide ? ei[di * 2] : ei[di];
    if ((unsigned)d < (unsigned)N_NODES && (unsigned)s < (unsigned)N_NODES) {
        int p = atomicAdd(&cursor[d], 1);
        srcs[p] = s;
    }
}

// ---------------- gather: agg[i] = (1+eps)*x[i] + sum_{j in N(i)} x[j] ----------------
__global__ __launch_bounds__(128) void k_gather(const float* __restrict__ x,
                                                const int* __restrict__ srcs,
                                                const int* __restrict__ offsets,
                                                const int* __restrict__ ends,
                                                float* __restrict__ agg) {
    __shared__ int sl[128];
    int node = blockIdx.x;
    int t = threadIdx.x;
    int beg = offsets[node];
    int end = ends[node];
    float acc = 1.001f * x[(size_t)node * D + t];
    for (int chunk = beg; chunk < end; chunk += 128) {
        int n = end - chunk; if (n > 128) n = 128;
        if (t < n) sl[t] = srcs[chunk + t];
        __syncthreads();
        for (int j = 0; j < n; ++j) {
            acc += x[(size_t)sl[j] * D + t];
        }
        __syncthreads();
    }
    agg[(size_t)node * D + t] = acc;
}

// ---------------- f32 GEMM: out[M,128] = A[M,128] @ W[128,128] + b, optional relu ----
// Block tile: 64 rows x 64 cols. 256 threads, thread tile 4x4. LDS ~64.25 KB -> 2 blk/CU.
__device__ inline void fma4(float4& c, float a, const float4& w) {
    c.x = fmaf(a, w.x, c.x);
    c.y = fmaf(a, w.y, c.y);
    c.z = fmaf(a, w.z, c.z);
    c.w = fmaf(a, w.w, c.w);
}

template <int RELU>
__global__ __launch_bounds__(256) void k_gemm(const float* __restrict__ A,
                                              const float* __restrict__ W,
                                              const float* __restrict__ bias,
                                              float* __restrict__ out) {
    __shared__ float Wl[128 * 64];   // [k][local col]
    __shared__ float Al[64 * 128];   // [local row][k]
    __shared__ float bl[64];
    int t = threadIdx.x;
    int row0 = (blockIdx.x >> 1) * 64;
    int col0 = (blockIdx.x & 1) * 64;

    const float4* W4g = (const float4*)W;
    float4* Wl4 = (float4*)Wl;
    for (int i = t; i < 2048; i += 256) {
        int k = i >> 4;      // 0..127
        int cq = i & 15;     // 0..15 -> local col quad
        Wl4[i] = W4g[k * 32 + (col0 >> 2) + cq];
    }
    if (t < 16) ((float4*)bl)[t] = ((const float4*)(bias + col0))[t];

    const float4* A4g = (const float4*)A;
    float4* Al4 = (float4*)Al;
    for (int i = t; i < 2048; i += 256) {
        int r = i >> 5;      // 0..63
        int kq = i & 31;     // 0..31
        int grow = row0 + r;
        float4 v = make_float4(0.f, 0.f, 0.f, 0.f);
        if (grow < N_NODES) v = A4g[(size_t)grow * 32 + kq];
        Al4[i] = v;
    }
    __syncthreads();

    int cq = t & 15;   // cols col0 + cq*4 .. +3
    int rg = t >> 4;   // rows row0 + rg*4 .. +3
    float4 bv = ((float4*)bl)[cq];
    float4 acc0 = bv, acc1 = bv, acc2 = bv, acc3 = bv;

    for (int kq = 0; kq < 32; ++kq) {
        float4 a0 = Al4[(rg * 4 + 0) * 32 + kq];
        float4 a1 = Al4[(rg * 4 + 1) * 32 + kq];
        float4 a2 = Al4[(rg * 4 + 2) * 32 + kq];
        float4 a3 = Al4[(rg * 4 + 3) * 32 + kq];
        float4 w0 = Wl4[(kq * 4 + 0) * 16 + cq];
        float4 w1 = Wl4[(kq * 4 + 1) * 16 + cq];
        float4 w2 = Wl4[(kq * 4 + 2) * 16 + cq];
        float4 w3 = Wl4[(kq * 4 + 3) * 16 + cq];
        fma4(acc0, a0.x, w0); fma4(acc0, a0.y, w1); fma4(acc0, a0.z, w2); fma4(acc0, a0.w, w3);
        fma4(acc1, a1.x, w0); fma4(acc1, a1.y, w1); fma4(acc1, a1.z, w2); fma4(acc1, a1.w, w3);
        fma4(acc2, a2.x, w0); fma4(acc2, a2.y, w1); fma4(acc2, a2.z, w2); fma4(acc2, a2.w, w3);
        fma4(acc3, a3.x, w0); fma4(acc3, a3.y, w1); fma4(acc3, a3.z, w2); fma4(acc3, a3.w, w3);
    }

    float4* out4 = (float4*)out;
    float4 accs[4] = {acc0, acc1, acc2, acc3};
    for (int r = 0; r < 4; ++r) {
        int grow = row0 + rg * 4 + r;
        if (grow < N_NODES) {
            float4 v = accs[r];
            if (RELU) {
                v.x = fmaxf(v.x, 0.f); v.y = fmaxf(v.y, 0.f);
                v.z = fmaxf(v.z, 0.f); v.w = fmaxf(v.w, 0.f);
            }
            out4[(size_t)grow * 32 + (col0 >> 2) + cq] = v;
        }
    }
}

extern "C" void kernel_launch(void* const* d_in, const int* in_sizes, int n_in,
                              void* d_out, int out_size, void* d_ws, size_t ws_size,
                              hipStream_t stream) {
    const float* x  = (const float*)d_in[0];
    const int*   ei = (const int*)d_in[1];
    const float* W1 = (const float*)d_in[2];
    const float* b1 = (const float*)d_in[3];
    const float* W2 = (const float*)d_in[4];
    const float* b2 = (const float*)d_in[5];
    float* out = (float*)d_out;

    // workspace layout (bytes)
    char* ws = (char*)d_ws;
    float* agg     = (float*)(ws);                       // 25,600,000 B
    float* h       = (float*)(ws + 25600000);            // 25,600,000 B
    int*   deg     = (int*)  (ws + 51200000);            //    200,000 B
    int*   offsets = (int*)  (ws + 51400000);            //    200,000 B
    int*   cursor  = (int*)  (ws + 51600000);            //    200,000 B
    int*   srcs    = (int*)  (ws + 51800000);            //  6,400,000 B
    int*   flag    = (int*)  (ws + 58200000);            //         16 B

    k_detect<<<1, 256, 0, stream>>>(ei, flag);
    k_zero<<<(N_NODES + 255) / 256, 256, 0, stream>>>(deg);
    k_hist<<<N_EDGES / 256, 256, 0, stream>>>(ei, flag, deg);
    k_scan<<<1, 1024, 0, stream>>>(deg, offsets, cursor);
    k_fill<<<N_EDGES / 256, 256, 0, stream>>>(ei, flag, cursor, srcs);
    k_gather<<<N_NODES, 128, 0, stream>>>(x, srcs, offsets, cursor, agg);

    int gblocks = 2 * ((N_NODES + 63) / 64);
    k_gemm<1><<<gblocks, 256, 0, stream>>>(agg, W1, b1, h);
    k_gemm<0><<<gblocks, 256, 0, stream>>>(h, W2, b2, out);
}

// Round 2
// 372.832 us; speedup vs baseline: 1.5031x; 1.5031x over previous
//
#include <hip/hip_runtime.h>
#include <hip/hip_bf16.h>

// GIN layer: out = relu(((1+eps)*x + segment_sum(x[src], dst)) @ W1 + b1) @ W2 + b2
// N=50000 nodes, E=1.6M edges, D=128.

#define N_NODES 50000
#define N_EDGES 1600000
#define D 128

// ---------------- edge dtype detection ----------------
// If edge_index is int64 (little-endian, values < 50000), every odd int32 word
// of the buffer is 0. If int32, odd words are random node ids (P(all 256 == 0) ~ 0).
__global__ void k_detect(const int* __restrict__ ei, int* __restrict__ flag) {
    __shared__ int nz;
    if (threadIdx.x == 0) nz = 0;
    __syncthreads();
    int v = ei[threadIdx.x * 2 + 1];
    if (v != 0) atomicAdd(&nz, 1);
    __syncthreads();
    if (threadIdx.x == 0) *flag = (nz == 0) ? 1 : 0;  // 1 => int64 layout
}

// ---------------- zero degree ----------------
__global__ void k_zero(int* __restrict__ deg) {
    int i = blockIdx.x * blockDim.x + threadIdx.x;
    if (i < N_NODES) deg[i] = 0;
}

// ---------------- histogram + per-edge rank (one atomic pass) ----------------
__global__ __launch_bounds__(512) void k_hist_rank(const int* __restrict__ ei,
                                                   const int* __restrict__ flag,
                                                   int* __restrict__ deg,
                                                   int* __restrict__ rank) {
    int wide = *flag;
    int T = gridDim.x * blockDim.x;
    for (int e = blockIdx.x * blockDim.x + threadIdx.x; e < N_EDGES; e += T) {
        long long di = (long long)N_EDGES + e;
        int d = wide ? ei[di * 2] : ei[di];
        int r = 0;
        if ((unsigned)d < (unsigned)N_NODES) r = atomicAdd(&deg[d], 1);
        rank[e] = r;  // coalesced
    }
}

// ---------------- multi-block exclusive scan over 50000 ----------------
// phase 1: per-block (512-wide) exclusive scan into offsets + block sums
__global__ __launch_bounds__(512) void k_scan1(const int* __restrict__ deg,
                                               int* __restrict__ offsets,
                                               int* __restrict__ bsum) {
    __shared__ int tmp[512];
    int t = threadIdx.x;
    int gid = blockIdx.x * 512 + t;
    int v = (gid < N_NODES) ? deg[gid] : 0;
    tmp[t] = v;
    __syncthreads();
    for (int off = 1; off < 512; off <<= 1) {
        int u = (t >= off) ? tmp[t - off] : 0;
        __syncthreads();
        tmp[t] += u;
        __syncthreads();
    }
    if (gid < N_NODES) offsets[gid] = tmp[t] - v;  // exclusive within block
    if (t == 511) bsum[blockIdx.x] = tmp[511];
}

// phase 2: scan the 98 block sums (exclusive)
__global__ __launch_bounds__(128) void k_scan2(int* __restrict__ bsum, int nb) {
    __shared__ int tmp[128];
    int t = threadIdx.x;
    int orig = (t < nb) ? bsum[t] : 0;
    tmp[t] = orig;
    __syncthreads();
    for (int off = 1; off < 128; off <<= 1) {
        int u = (t >= off) ? tmp[t - off] : 0;
        __syncthreads();
        tmp[t] += u;
        __syncthreads();
    }
    if (t < nb) bsum[t] = tmp[t] - orig;  // exclusive, in place
}

// phase 3: add block base in place
__global__ __launch_bounds__(512) void k_scan3(int* __restrict__ offsets,
                                               const int* __restrict__ bsum) {
    int gid = blockIdx.x * 512 + threadIdx.x;
    if (gid < N_NODES) offsets[gid] += bsum[blockIdx.x];
}

// ---------------- CSR place (no atomics) ----------------
__global__ __launch_bounds__(512) void k_place(const int* __restrict__ ei,
                                               const int* __restrict__ flag,
                                               const int* __restrict__ offsets,
                                               const int* __restrict__ rank,
                                               int* __restrict__ srcs) {
    int wide = *flag;
    int T = gridDim.x * blockDim.x;
    for (int e = blockIdx.x * blockDim.x + threadIdx.x; e < N_EDGES; e += T) {
        int s = wide ? ei[(long long)e * 2] : ei[e];
        long long di = (long long)N_EDGES + e;
        int d = wide ? ei[di * 2] : ei[di];
        if ((unsigned)d < (unsigned)N_NODES && (unsigned)s < (unsigned)N_NODES)
            srcs[offsets[d] + rank[e]] = s;  // scattered, no dependency
    }
}

// ---------------- gather: agg[i] = (1+eps)*x[i] + sum_{j in N(i)} x[j] ----------------
// 256 threads/node: 8 neighbor groups x 32 col-quads (float4), LDS tree reduce.
__global__ __launch_bounds__(256) void k_gather(const float* __restrict__ x,
                                                const int* __restrict__ srcs,
                                                const int* __restrict__ offsets,
                                                const int* __restrict__ deg,
                                                float* __restrict__ agg) {
    int node = blockIdx.x;
    int t = threadIdx.x;
    int cq = t & 31;   // column quad 0..31
    int g = t >> 5;    // neighbor group 0..7
    int beg = offsets[node];
    int end = beg + deg[node];
    const float4* x4 = (const float4*)x;
    float4 acc = make_float4(0.f, 0.f, 0.f, 0.f);
    for (int j = beg + g; j < end; j += 8) {
        int s = srcs[j];
        float4 v = x4[(size_t)s * 32 + cq];
        acc.x += v.x; acc.y += v.y; acc.z += v.z; acc.w += v.w;
    }
    __shared__ float4 red[8][32];
    red[g][cq] = acc;
    __syncthreads();
    if (t < 32) {
        float4 r = red[0][t];
        #pragma unroll
        for (int k = 1; k < 8; ++k) {
            float4 v = red[k][t];
            r.x += v.x; r.y += v.y; r.z += v.z; r.w += v.w;
        }
        float4 xs = x4[(size_t)node * 32 + t];
        r.x = fmaf(1.001f, xs.x, r.x);
        r.y = fmaf(1.001f, xs.y, r.y);
        r.z = fmaf(1.001f, xs.z, r.z);
        r.w = fmaf(1.001f, xs.w, r.w);
        ((float4*)agg)[(size_t)node * 32 + t] = r;
    }
}

// ---------------- f32 GEMM: out[M,128] = A[M,128] @ W[128,128] + b, optional relu ----
__device__ inline void fma4(float4& c, float a, const float4& w) {
    c.x = fmaf(a, w.x, c.x);
    c.y = fmaf(a, w.y, c.y);
    c.z = fmaf(a, w.z, c.z);
    c.w = fmaf(a, w.w, c.w);
}

template <int RELU>
__global__ __launch_bounds__(256) void k_gemm(const float* __restrict__ A,
                                              const float* __restrict__ W,
                                              const float* __restrict__ bias,
                                              float* __restrict__ out) {
    __shared__ float Wl[128 * 64];   // [k][local col]
    __shared__ float Al[64 * 128];   // [local row][k]
    __shared__ float bl[64];
    int t = threadIdx.x;
    int row0 = (blockIdx.x >> 1) * 64;
    int col0 = (blockIdx.x & 1) * 64;

    const float4* W4g = (const float4*)W;
    float4* Wl4 = (float4*)Wl;
    for (int i = t; i < 2048; i += 256) {
        int k = i >> 4;      // 0..127
        int cq = i & 15;     // 0..15 -> local col quad
        Wl4[i] = W4g[k * 32 + (col0 >> 2) + cq];
    }
    if (t < 16) ((float4*)bl)[t] = ((const float4*)(bias + col0))[t];

    const float4* A4g = (const float4*)A;
    float4* Al4 = (float4*)Al;
    for (int i = t; i < 2048; i += 256) {
        int r = i >> 5;      // 0..63
        int kq = i & 31;     // 0..31
        int grow = row0 + r;
        float4 v = make_float4(0.f, 0.f, 0.f, 0.f);
        if (grow < N_NODES) v = A4g[(size_t)grow * 32 + kq];
        Al4[i] = v;
    }
    __syncthreads();

    int cq = t & 15;   // cols col0 + cq*4 .. +3
    int rg = t >> 4;   // rows row0 + rg*4 .. +3
    float4 bv = ((float4*)bl)[cq];
    float4 acc0 = bv, acc1 = bv, acc2 = bv, acc3 = bv;

    for (int kq = 0; kq < 32; ++kq) {
        float4 a0 = Al4[(rg * 4 + 0) * 32 + kq];
        float4 a1 = Al4[(rg * 4 + 1) * 32 + kq];
        float4 a2 = Al4[(rg * 4 + 2) * 32 + kq];
        float4 a3 = Al4[(rg * 4 + 3) * 32 + kq];
        float4 w0 = Wl4[(kq * 4 + 0) * 16 + cq];
        float4 w1 = Wl4[(kq * 4 + 1) * 16 + cq];
        float4 w2 = Wl4[(kq * 4 + 2) * 16 + cq];
        float4 w3 = Wl4[(kq * 4 + 3) * 16 + cq];
        fma4(acc0, a0.x, w0); fma4(acc0, a0.y, w1); fma4(acc0, a0.z, w2); fma4(acc0, a0.w, w3);
        fma4(acc1, a1.x, w0); fma4(acc1, a1.y, w1); fma4(acc1, a1.z, w2); fma4(acc1, a1.w, w3);
        fma4(acc2, a2.x, w0); fma4(acc2, a2.y, w1); fma4(acc2, a2.z, w2); fma4(acc2, a2.w, w3);
        fma4(acc3, a3.x, w0); fma4(acc3, a3.y, w1); fma4(acc3, a3.z, w2); fma4(acc3, a3.w, w3);
    }

    float4* out4 = (float4*)out;
    float4 accs[4] = {acc0, acc1, acc2, acc3};
    for (int r = 0; r < 4; ++r) {
        int grow = row0 + rg * 4 + r;
        if (grow < N_NODES) {
            float4 v = accs[r];
            if (RELU) {
                v.x = fmaxf(v.x, 0.f); v.y = fmaxf(v.y, 0.f);
                v.z = fmaxf(v.z, 0.f); v.w = fmaxf(v.w, 0.f);
            }
            out4[(size_t)grow * 32 + (col0 >> 2) + cq] = v;
        }
    }
}

extern "C" void kernel_launch(void* const* d_in, const int* in_sizes, int n_in,
                              void* d_out, int out_size, void* d_ws, size_t ws_size,
                              hipStream_t stream) {
    const float* x  = (const float*)d_in[0];
    const int*   ei = (const int*)d_in[1];
    const float* W1 = (const float*)d_in[2];
    const float* b1 = (const float*)d_in[3];
    const float* W2 = (const float*)d_in[4];
    const float* b2 = (const float*)d_in[5];
    float* out = (float*)d_out;

    // workspace layout (bytes); rank+srcs alias h's region (dead before GEMM1 writes h)
    char* ws = (char*)d_ws;
    float* agg     = (float*)(ws);                       // [0, 25.6e6)
    float* h       = (float*)(ws + 25600000);            // [25.6e6, 51.2e6)
    int*   rank    = (int*)  (ws + 25600000);            //   alias: first 6.4 MB of h
    int*   srcs    = (int*)  (ws + 32000000);            //   alias: next 6.4 MB of h
    int*   deg     = (int*)  (ws + 51200000);            // 200 KB
    int*   offsets = (int*)  (ws + 51400000);            // 200 KB
    int*   bsum    = (int*)  (ws + 51600000);            // 4 KB
    int*   flag    = (int*)  (ws + 51610000);            // 16 B

    const int NB_SCAN = (N_NODES + 511) / 512;  // 98

    k_detect<<<1, 256, 0, stream>>>(ei, flag);
    k_zero<<<(N_NODES + 255) / 256, 256, 0, stream>>>(deg);
    k_hist_rank<<<1024, 512, 0, stream>>>(ei, flag, deg, rank);
    k_scan1<<<NB_SCAN, 512, 0, stream>>>(deg, offsets, bsum);
    k_scan2<<<1, 128, 0, stream>>>(bsum, NB_SCAN);
    k_scan3<<<NB_SCAN, 512, 0, stream>>>(offsets, bsum);
    k_place<<<1024, 512, 0, stream>>>(ei, flag, offsets, rank, srcs);
    k_gather<<<N_NODES, 256, 0, stream>>>(x, srcs, offsets, deg, agg);

    int gblocks = 2 * ((N_NODES + 63) / 64);
    k_gemm<1><<<gblocks, 256, 0, stream>>>(agg, W1, b1, h);
    k_gemm<0><<<gblocks, 256, 0, stream>>>(h, W2, b2, out);
}

// Round 3
// 309.095 us; speedup vs baseline: 1.8130x; 1.2062x over previous
//
#include <hip/hip_runtime.h>
#include <hip/hip_bf16.h>

// GIN layer: out = relu(((1+eps)*x + segment_sum(x[src], dst)) @ W1 + b1) @ W2 + b2
// N=50000 nodes, E=1.6M edges, D=128.

#define N_NODES 50000
#define N_EDGES 1600000
#define D 128

typedef __attribute__((ext_vector_type(8))) short short8;
typedef __attribute__((ext_vector_type(4))) float float4v;

__device__ inline unsigned short f2b(float f) {
    unsigned u = __builtin_bit_cast(unsigned, f);
    u = u + 0x7fffu + ((u >> 16) & 1u);  // RNE (inputs are finite, no NaN concern)
    return (unsigned short)(u >> 16);
}
__device__ inline float b2f_lo(unsigned u) { return __builtin_bit_cast(float, u << 16); }
__device__ inline float b2f_hi(unsigned u) { return __builtin_bit_cast(float, u & 0xffff0000u); }

// ---------------- edge dtype detection ----------------
__global__ void k_detect(const int* __restrict__ ei, int* __restrict__ flag) {
    __shared__ int nz;
    if (threadIdx.x == 0) nz = 0;
    __syncthreads();
    int v = ei[threadIdx.x * 2 + 1];
    if (v != 0) atomicAdd(&nz, 1);
    __syncthreads();
    if (threadIdx.x == 0) *flag = (nz == 0) ? 1 : 0;  // 1 => int64 layout
}

// ---------------- x f32 -> packed bf16 ----------------
__global__ __launch_bounds__(256) void k_cvt(const float* __restrict__ x,
                                             unsigned short* __restrict__ xb) {
    int i = blockIdx.x * blockDim.x + threadIdx.x;  // one float4 per thread
    if (i >= N_NODES * (D / 4)) return;
    float4 v = ((const float4*)x)[i];
    ushort4 o;
    o.x = f2b(v.x); o.y = f2b(v.y); o.z = f2b(v.z); o.w = f2b(v.w);
    ((ushort4*)xb)[i] = o;
}

// ---------------- zero degree ----------------
__global__ void k_zero(int* __restrict__ deg) {
    int i = blockIdx.x * blockDim.x + threadIdx.x;
    if (i < N_NODES) deg[i] = 0;
}

// ---------------- histogram + per-edge rank ----------------
__global__ __launch_bounds__(512) void k_hist_rank(const int* __restrict__ ei,
                                                   const int* __restrict__ flag,
                                                   int* __restrict__ deg,
                                                   int* __restrict__ rank) {
    int wide = *flag;
    int T = gridDim.x * blockDim.x;
    for (int e = blockIdx.x * blockDim.x + threadIdx.x; e < N_EDGES; e += T) {
        long long di = (long long)N_EDGES + e;
        int d = wide ? ei[di * 2] : ei[di];
        int r = 0;
        if ((unsigned)d < (unsigned)N_NODES) r = atomicAdd(&deg[d], 1);
        rank[e] = r;
    }
}

// ---------------- multi-block exclusive scan ----------------
__global__ __launch_bounds__(512) void k_scan1(const int* __restrict__ deg,
                                               int* __restrict__ offsets,
                                               int* __restrict__ bsum) {
    __shared__ int tmp[512];
    int t = threadIdx.x;
    int gid = blockIdx.x * 512 + t;
    int v = (gid < N_NODES) ? deg[gid] : 0;
    tmp[t] = v;
    __syncthreads();
    for (int off = 1; off < 512; off <<= 1) {
        int u = (t >= off) ? tmp[t - off] : 0;
        __syncthreads();
        tmp[t] += u;
        __syncthreads();
    }
    if (gid < N_NODES) offsets[gid] = tmp[t] - v;
    if (t == 511) bsum[blockIdx.x] = tmp[511];
}

__global__ __launch_bounds__(128) void k_scan2(int* __restrict__ bsum, int nb) {
    __shared__ int tmp[128];
    int t = threadIdx.x;
    int orig = (t < nb) ? bsum[t] : 0;
    tmp[t] = orig;
    __syncthreads();
    for (int off = 1; off < 128; off <<= 1) {
        int u = (t >= off) ? tmp[t - off] : 0;
        __syncthreads();
        tmp[t] += u;
        __syncthreads();
    }
    if (t < nb) bsum[t] = tmp[t] - orig;
}

__global__ __launch_bounds__(512) void k_scan3(int* __restrict__ offsets,
                                               const int* __restrict__ bsum) {
    int gid = blockIdx.x * 512 + threadIdx.x;
    if (gid < N_NODES) offsets[gid] += bsum[blockIdx.x];
}

// ---------------- CSR place (no atomics) ----------------
__global__ __launch_bounds__(512) void k_place(const int* __restrict__ ei,
                                               const int* __restrict__ flag,
                                               const int* __restrict__ offsets,
                                               const int* __restrict__ rank,
                                               int* __restrict__ srcs) {
    int wide = *flag;
    int T = gridDim.x * blockDim.x;
    for (int e = blockIdx.x * blockDim.x + threadIdx.x; e < N_EDGES; e += T) {
        int s = wide ? ei[(long long)e * 2] : ei[e];
        long long di = (long long)N_EDGES + e;
        int d = wide ? ei[di * 2] : ei[di];
        if ((unsigned)d < (unsigned)N_NODES && (unsigned)s < (unsigned)N_NODES)
            srcs[offsets[d] + rank[e]] = s;
    }
}

// ---------------- gather (bf16 x): agg[i] = (1+eps)*x[i] + sum x[j] ----------------
// 256 threads/node: 8 neighbor groups x 32 lanes; each lane: uint2 = 4 bf16 cols.
__global__ __launch_bounds__(256) void k_gather(const float* __restrict__ x,
                                                const unsigned short* __restrict__ xb,
                                                const int* __restrict__ srcs,
                                                const int* __restrict__ offsets,
                                                const int* __restrict__ deg,
                                                float* __restrict__ agg) {
    int node = blockIdx.x;
    int t = threadIdx.x;
    int cq = t & 31;   // uint2 index 0..31 (4 bf16 each = 128 cols)
    int g = t >> 5;    // neighbor group 0..7
    int beg = offsets[node];
    int end = beg + deg[node];
    const uint2* xr = (const uint2*)xb;
    float4 acc = make_float4(0.f, 0.f, 0.f, 0.f);
    #pragma unroll 2
    for (int j = beg + g; j < end; j += 8) {
        int s = srcs[j];
        uint2 a = xr[(size_t)s * 32 + cq];
        acc.x += b2f_lo(a.x); acc.y += b2f_hi(a.x);
        acc.z += b2f_lo(a.y); acc.w += b2f_hi(a.y);
    }
    __shared__ float4 red[8][32];
    red[g][cq] = acc;
    __syncthreads();
    if (t < 32) {
        float4 r = red[0][t];
        #pragma unroll
        for (int k = 1; k < 8; ++k) {
            float4 v = red[k][t];
            r.x += v.x; r.y += v.y; r.z += v.z; r.w += v.w;
        }
        float4 xs = ((const float4*)x)[(size_t)node * 32 + t];
        r.x = fmaf(1.001f, xs.x, r.x);
        r.y = fmaf(1.001f, xs.y, r.y);
        r.z = fmaf(1.001f, xs.z, r.z);
        r.w = fmaf(1.001f, xs.w, r.w);
        ((float4*)agg)[(size_t)node * 32 + t] = r;
    }
}

// ---------------- bf16 MFMA GEMM: out[M,128] = A[M,128] @ W[128,128] + b ----------------
// Block: 128 rows x 128 cols, 256 threads (4 waves). Wave: 32 rows (2 m-tiles) x 8 n-tiles.
// A and W^T staged in LDS as bf16, rows padded to 136 shorts (272 B: 16B-aligned frags).
#define LPAD 136
template <int RELU>
__global__ __launch_bounds__(256, 2) void k_gemm(const float* __restrict__ A,
                                                 const float* __restrict__ Wg,
                                                 const float* __restrict__ bias,
                                                 float* __restrict__ out, int M) {
    __shared__ short Al[128 * LPAD];   // [row][k]
    __shared__ short Wt[128 * LPAD];   // [n][k]  (transposed W)
    __shared__ float bl[128];

    int t = threadIdx.x;
    int row0 = blockIdx.x * 128;

    // stage A (f32 -> bf16), coalesced float4 reads
    const float4* A4 = (const float4*)A;
    #pragma unroll
    for (int i = 0; i < 16; ++i) {
        int idx = i * 256 + t;
        int r = idx >> 5;       // 0..127
        int c4 = idx & 31;      // float4 col
        float4 v = make_float4(0.f, 0.f, 0.f, 0.f);
        if (row0 + r < M) v = A4[(size_t)(row0 + r) * 32 + c4];
        ushort4 o;
        o.x = f2b(v.x); o.y = f2b(v.y); o.z = f2b(v.z); o.w = f2b(v.w);
        *(ushort4*)&Al[r * LPAD + c4 * 4] = o;
    }
    // stage W transposed (f32 -> bf16)
    const float4* W4 = (const float4*)Wg;
    #pragma unroll
    for (int i = 0; i < 16; ++i) {
        int idx = i * 256 + t;
        int k = idx >> 5;       // 0..127
        int n4 = idx & 31;      // float4 col group
        float4 v = W4[k * 32 + n4];
        Wt[(n4 * 4 + 0) * LPAD + k] = (short)f2b(v.x);
        Wt[(n4 * 4 + 1) * LPAD + k] = (short)f2b(v.y);
        Wt[(n4 * 4 + 2) * LPAD + k] = (short)f2b(v.z);
        Wt[(n4 * 4 + 3) * LPAD + k] = (short)f2b(v.w);
    }
    if (t < 32) ((float4*)bl)[t] = ((const float4*)bias)[t];
    __syncthreads();

    int wave = t >> 6;
    int lane = t & 63;
    int quad = lane >> 4;
    int l16 = lane & 15;
    int rowbase = wave * 32;  // within block

    float4v acc[2][8];
    #pragma unroll
    for (int mt = 0; mt < 2; ++mt)
        #pragma unroll
        for (int nt = 0; nt < 8; ++nt)
            acc[mt][nt] = (float4v){0.f, 0.f, 0.f, 0.f};

    #pragma unroll
    for (int kc = 0; kc < 4; ++kc) {
        int koff = kc * 32 + quad * 8;
        short8 a0 = *(const short8*)&Al[(rowbase + l16) * LPAD + koff];
        short8 a1 = *(const short8*)&Al[(rowbase + 16 + l16) * LPAD + koff];
        #pragma unroll
        for (int nt = 0; nt < 8; ++nt) {
            short8 b = *(const short8*)&Wt[(nt * 16 + l16) * LPAD + koff];
            acc[0][nt] = __builtin_amdgcn_mfma_f32_16x16x32_bf16(a0, b, acc[0][nt], 0, 0, 0);
            acc[1][nt] = __builtin_amdgcn_mfma_f32_16x16x32_bf16(a1, b, acc[1][nt], 0, 0, 0);
        }
    }

    // epilogue: D[row=(lane>>4)*4+reg][col=lane&15] per tile
    #pragma unroll
    for (int mt = 0; mt < 2; ++mt) {
        int rloc = rowbase + mt * 16 + quad * 4;
        #pragma unroll
        for (int nt = 0; nt < 8; ++nt) {
            int col = nt * 16 + l16;
            float bv = bl[col];
            #pragma unroll
            for (int r = 0; r < 4; ++r) {
                int grow = row0 + rloc + r;
                if (grow < M) {
                    float v = acc[mt][nt][r] + bv;
                    if (RELU) v = fmaxf(v, 0.f);
                    out[(size_t)grow * 128 + col] = v;
                }
            }
        }
    }
}

extern "C" void kernel_launch(void* const* d_in, const int* in_sizes, int n_in,
                              void* d_out, int out_size, void* d_ws, size_t ws_size,
                              hipStream_t stream) {
    const float* x  = (const float*)d_in[0];
    const int*   ei = (const int*)d_in[1];
    const float* W1 = (const float*)d_in[2];
    const float* b1 = (const float*)d_in[3];
    const float* W2 = (const float*)d_in[4];
    const float* b2 = (const float*)d_in[5];
    float* out = (float*)d_out;

    // workspace layout; rank/srcs/xb alias h's region (all dead before GEMM1 writes h)
    char* ws = (char*)d_ws;
    float*          agg     = (float*)(ws);                  // [0, 25.6e6)
    float*          h       = (float*)(ws + 25600000);       // [25.6e6, 51.2e6)
    int*            rank    = (int*)  (ws + 25600000);       //   alias
    int*            srcs    = (int*)  (ws + 32000000);       //   alias
    unsigned short* xb      = (unsigned short*)(ws + 38400000); // alias, 12.8 MB
    int*            deg     = (int*)  (ws + 51200000);
    int*            offsets = (int*)  (ws + 51400000);
    int*            bsum    = (int*)  (ws + 51600000);
    int*            flag    = (int*)  (ws + 51610000);

    const int NB_SCAN = (N_NODES + 511) / 512;  // 98

    k_detect<<<1, 256, 0, stream>>>(ei, flag);
    k_cvt<<<(N_NODES * (D / 4) + 255) / 256, 256, 0, stream>>>(x, xb);
    k_zero<<<(N_NODES + 255) / 256, 256, 0, stream>>>(deg);
    k_hist_rank<<<1024, 512, 0, stream>>>(ei, flag, deg, rank);
    k_scan1<<<NB_SCAN, 512, 0, stream>>>(deg, offsets, bsum);
    k_scan2<<<1, 128, 0, stream>>>(bsum, NB_SCAN);
    k_scan3<<<NB_SCAN, 512, 0, stream>>>(offsets, bsum);
    k_place<<<1024, 512, 0, stream>>>(ei, flag, offsets, rank, srcs);
    k_gather<<<N_NODES, 256, 0, stream>>>(x, xb, srcs, offsets, deg, agg);

    int gblocks = (N_NODES + 127) / 128;  // 391
    k_gemm<1><<<gblocks, 256, 0, stream>>>(agg, W1, b1, h, N_NODES);
    k_gemm<0><<<gblocks, 256, 0, stream>>>(h, W2, b2, out, N_NODES);
}